// Round 9
// baseline (800.787 us; speedup 1.0000x reference)
//
#include <hip/hip_runtime.h>

// ---------------------------------------------------------------------------
// GRANGER — R25: two independent barrier domains per CU.
// Occupancy fact: at 128 VGPR the HW allows 16 waves/CU; nets LDS 49KB <= 80KB
// -> TWO 512-thr blocks can co-reside. Current grid (64,4) supplies one ->
// all 8 waves lockstep behind one barrier (surviving theory: phase stalls,
// MfmaUtil 22 + VALUBusy 40 on separate pipes = ~45% idle each).
// Change: grid (64,8), 8 rows/block. Fragment geometry untouched; rows 8-15
// compute bounded garbage (MFMA rows are independent), never stored; valid
// rows bit-exact. Guards: head/out writes row<8; znoise/h1g clamped; xs
// zero-inited both buffers; staging tid<128; out tid<8.
// Bet: two anti-phase blocks fill each other's pipe bubbles (m114: MFMA wave
// + VALU wave co-schedule, time ~ max not sum).
// Encoder_core: R24-exact (vectorized staging, ~75 us).
// Output layout (fp32): pred[P,B,L,1] | log_var[B,H] | mu[B,H] | mean_[B,P]
// | disp_[B,P]
// ---------------------------------------------------------------------------

#define OFF_LV   409600
#define OFF_MU   425984
#define OFF_MEAN 442368
#define OFF_DISP 446464

typedef __attribute__((ext_vector_type(8))) short  bf16x8;
typedef __attribute__((ext_vector_type(4))) float  f32x4;

__device__ __forceinline__ float bf2f(unsigned short u) {
    union { unsigned int i; float f; } v; v.i = ((unsigned int)u) << 16; return v.f;
}
__device__ __forceinline__ unsigned short f2bf(float f) {
    union { float f; unsigned int i; } v; v.f = f;
    unsigned int x = v.i;
    return (unsigned short)((x + 0x7FFFu + ((x >> 16) & 1u)) >> 16);
}
__device__ __forceinline__ unsigned short f2bf_fast(float f) {
    return (unsigned short)((__float_as_uint(f) + 0x8000u) >> 16);
}
__device__ __forceinline__ bf16x8 pack8(const float* pf) {
    union { unsigned int u[4]; bf16x8 v; } r;
    const float4 a = *(const float4*)pf;
    const float4 b = *(const float4*)(pf + 4);
    r.u[0] = ((__float_as_uint(a.x) + 0x8000u) >> 16) | ((__float_as_uint(a.y) + 0x8000u) & 0xFFFF0000u);
    r.u[1] = ((__float_as_uint(a.z) + 0x8000u) >> 16) | ((__float_as_uint(a.w) + 0x8000u) & 0xFFFF0000u);
    r.u[2] = ((__float_as_uint(b.x) + 0x8000u) >> 16) | ((__float_as_uint(b.y) + 0x8000u) & 0xFFFF0000u);
    r.u[3] = ((__float_as_uint(b.z) + 0x8000u) >> 16) | ((__float_as_uint(b.w) + 0x8000u) & 0xFFFF0000u);
    return r.v;
}
__device__ __forceinline__ ushort4 f2bf4(float4 v) {
    ushort4 w;
    w.x = f2bf_fast(v.x); w.y = f2bf_fast(v.y);
    w.z = f2bf_fast(v.z); w.w = f2bf_fast(v.w);
    return w;
}
// rcpf-based, inf-safe
__device__ __forceinline__ float sigm(float x) {
    return __builtin_amdgcn_rcpf(1.0f + __expf(-x));
}
__device__ __forceinline__ float tanh_fast(float x) {
    return 2.0f * __builtin_amdgcn_rcpf(1.0f + __expf(-2.0f * x)) - 1.0f;
}
// Sum across the 16-lane DPP row via row_shr prefix adds (VALU pipe, no DS).
// Result valid in the LAST lane of each row (ncol==15). Verified R20/R21.
__device__ __forceinline__ float row_sum16(float v) {
    float t;
    t = __int_as_float(__builtin_amdgcn_update_dpp(0, __float_as_int(v), 0x111, 0xf, 0xf, true)); v += t; // shr:1
    t = __int_as_float(__builtin_amdgcn_update_dpp(0, __float_as_int(v), 0x112, 0xf, 0xf, true)); v += t; // shr:2
    t = __int_as_float(__builtin_amdgcn_update_dpp(0, __float_as_int(v), 0x114, 0xf, 0xf, true)); v += t; // shr:4
    t = __int_as_float(__builtin_amdgcn_update_dpp(0, __float_as_int(v), 0x118, 0xf, 0xf, true)); v += t; // shr:8
    return v;
}

#define MFMA(a, b, c) __builtin_amdgcn_mfma_f32_16x16x32_bf16((a), (b), (c), 0, 0, 0)

// ---------------------------------------------------------------------------
// Encoder core: R24-exact. 4 blocks x 512 thr; W_hh_left register-resident;
// W_ih_left in LDS (vectorized stage); 10 steps + gru_1; h1 -> d_ws (bf16).
// ---------------------------------------------------------------------------
__global__ __launch_bounds__(512, 1) void encoder_core(
    const float* __restrict__ X,
    const float* __restrict__ Wihl_f, const float* __restrict__ Whhl_f,
    const float* __restrict__ bihl,   const float* __restrict__ bhhl,
    const float* __restrict__ Wih1_f, const float* __restrict__ bih1,
    const float* __restrict__ bhh1,
    unsigned short* __restrict__ h1out)
{
    const int b0   = blockIdx.x * 16;
    const int tid  = threadIdx.x;
    const int wave = tid >> 6;
    const int lane = tid & 63;
    const int quad = lane >> 4;
    const int ncol = lane & 15;
    const int j0   = wave * 32 + ncol;
    const int j1   = j0 + 16;

    __shared__ __align__(16) unsigned short hs[2][16][264];
    __shared__ __align__(16) unsigned short xs[2][16][72];
    __shared__ __align__(16) unsigned short wihl_s[768][72];  // bf16, pad 64->72
    __shared__ float bR[256], bZ[256], bIN[256], bHN[256];
    __shared__ float b1R[256], b1Z[256], b1IN[256], b1HN[256];

    // stage W_ih_left -> LDS (bf16), 768x64, float4-vectorized
    {
        const float4* src = (const float4*)Wihl_f;
        for (int i = tid; i < 768 * 64 / 4; i += 512) {
            int idx = i * 4;
            int row = idx >> 6, col = idx & 63;
            *(ushort4*)&wihl_s[row][col] = f2bf4(src[i]);
        }
    }
    for (int i = tid; i < 256; i += 512) {
        bR[i]   = bihl[i]       + bhhl[i];
        bZ[i]   = bihl[256 + i] + bhhl[256 + i];
        bIN[i]  = bihl[512 + i];
        bHN[i]  = bhhl[512 + i];
        b1R[i]  = bih1[i]       + bhh1[i];
        b1Z[i]  = bih1[256 + i] + bhh1[256 + i];
        b1IN[i] = bih1[512 + i];
        b1HN[i] = bhh1[512 + i];
    }
    for (int i = tid; i < 16 * 264; i += 512)
        (&hs[0][0][0])[i] = 0;                       // h0 = 0
    for (int i = tid; i < 256; i += 512) {
        int b = i >> 4, f = (i & 15) * 4;
        float4 v = *(const float4*)&X[((size_t)(b0 + b) * 110 + 0) * 64 + f];
        *(ushort4*)&xs[0][b][f] = f2bf4(v);
    }

    // preload W_hh_left fragments into registers (loop-invariant, 192 regs)
    bf16x8 w_r[2][8], w_z[2][8], w_n[2][8];
    #pragma unroll
    for (int s = 0; s < 2; s++) {
        const int j = s ? j1 : j0;
        #pragma unroll
        for (int k0 = 0; k0 < 8; k0++) {
            const int ko = k0 * 32 + quad * 8;
            w_r[s][k0] = pack8(Whhl_f + (size_t)(j)       * 256 + ko);
            w_z[s][k0] = pack8(Whhl_f + (size_t)(256 + j) * 256 + ko);
            w_n[s][k0] = pack8(Whhl_f + (size_t)(512 + j) * 256 + ko);
        }
    }

    float hreg[2][4];
    #pragma unroll
    for (int s = 0; s < 2; s++)
        #pragma unroll
        for (int r = 0; r < 4; r++) hreg[s][r] = 0.f;

    __syncthreads();

    // ---- gru_left: 10 MFMA steps ----
    for (int t = 0; t < 10; t++) {
        const int cur = t & 1, nxt = cur ^ 1;
        f32x4 acc_r[2]  = {{0,0,0,0},{0,0,0,0}};
        f32x4 acc_z[2]  = {{0,0,0,0},{0,0,0,0}};
        f32x4 acc_in[2] = {{0,0,0,0},{0,0,0,0}};
        f32x4 acc_hn[2] = {{0,0,0,0},{0,0,0,0}};

        #pragma unroll
        for (int ks = 0; ks < 2; ks++) {
            const int ko = ks * 32 + quad * 8;
            bf16x8 a = *(const bf16x8*)&xs[cur][ncol][ko];
            #pragma unroll
            for (int s = 0; s < 2; s++) {
                const int j = s ? j1 : j0;
                bf16x8 br = *(const bf16x8*)&wihl_s[j][ko];
                bf16x8 bz = *(const bf16x8*)&wihl_s[256 + j][ko];
                bf16x8 bn = *(const bf16x8*)&wihl_s[512 + j][ko];
                acc_r[s]  = MFMA(a, br, acc_r[s]);
                acc_z[s]  = MFMA(a, bz, acc_z[s]);
                acc_in[s] = MFMA(a, bn, acc_in[s]);
            }
        }
        #pragma unroll
        for (int ks = 0; ks < 8; ks++) {
            bf16x8 a = *(const bf16x8*)&hs[cur][ncol][ks * 32 + quad * 8];
            #pragma unroll
            for (int s = 0; s < 2; s++) {
                acc_r[s]  = MFMA(a, w_r[s][ks], acc_r[s]);
                acc_z[s]  = MFMA(a, w_z[s][ks], acc_z[s]);
                acc_hn[s] = MFMA(a, w_n[s][ks], acc_hn[s]);
            }
        }
        #pragma unroll
        for (int s = 0; s < 2; s++) {
            const int j = s ? j1 : j0;
            #pragma unroll
            for (int r = 0; r < 4; r++) {
                float rg = sigm(acc_r[s][r] + bR[j]);
                float zg = sigm(acc_z[s][r] + bZ[j]);
                float nn = tanh_fast(acc_in[s][r] + bIN[j] + rg * (acc_hn[s][r] + bHN[j]));
                float hv = (1.f - zg) * nn + zg * hreg[s][r];
                hreg[s][r] = hv;
                hs[nxt][quad * 4 + r][j] = f2bf(hv);
            }
        }
        if (t < 9)
            for (int i = tid; i < 256; i += 512) {
                int b = i >> 4, f = (i & 15) * 4;
                float4 v = *(const float4*)&X[((size_t)(b0 + b) * 110 + (t + 1)) * 64 + f];
                *(ushort4*)&xs[nxt][b][f] = f2bf4(v);
            }
        __syncthreads();
    }
    // h_left in hs[0]

    // ---- gru_1 ----
    {
        f32x4 acc_r[2]  = {{0,0,0,0},{0,0,0,0}};
        f32x4 acc_z[2]  = {{0,0,0,0},{0,0,0,0}};
        f32x4 acc_in[2] = {{0,0,0,0},{0,0,0,0}};
        #pragma unroll 2
        for (int ks = 0; ks < 8; ks++) {
            const int ko = ks * 32 + quad * 8;
            bf16x8 a = *(const bf16x8*)&hs[0][ncol][ko];
            #pragma unroll
            for (int s = 0; s < 2; s++) {
                const int j = s ? j1 : j0;
                bf16x8 br = pack8(Wih1_f + (size_t)(j)       * 256 + ko);
                bf16x8 bz = pack8(Wih1_f + (size_t)(256 + j) * 256 + ko);
                bf16x8 bn = pack8(Wih1_f + (size_t)(512 + j) * 256 + ko);
                acc_r[s]  = MFMA(a, br, acc_r[s]);
                acc_z[s]  = MFMA(a, bz, acc_z[s]);
                acc_in[s] = MFMA(a, bn, acc_in[s]);
            }
        }
        #pragma unroll
        for (int s = 0; s < 2; s++) {
            const int j = s ? j1 : j0;
            #pragma unroll
            for (int r = 0; r < 4; r++) {
                float rg = sigm(acc_r[s][r] + b1R[j]);
                float zg = sigm(acc_z[s][r] + b1Z[j]);
                float nn = tanh_fast(acc_in[s][r] + b1IN[j] + rg * b1HN[j]);
                float hv = (1.f - zg) * nn;           // + zg*0
                hs[1][quad * 4 + r][j] = f2bf(hv);
            }
        }
        __syncthreads();   // h1 in hs[1]
    }

    for (int i = tid; i < 16 * 256; i += 512) {
        int row = i >> 8, j = i & 255;
        h1out[(size_t)(b0 + row) * 256 + j] = hs[1][row][j];
    }
}

// ---------------------------------------------------------------------------
// Nets: R21/R24 compute loop, 8 rows/block, grid (p=64, btile=8) = 512 blocks
// -> 2 blocks/CU (16 waves at 128 VGPR, 2x49KB LDS). Rows 8-15 of fragments
// compute bounded garbage, never stored; valid rows bit-exact.
// ---------------------------------------------------------------------------
__global__ __launch_bounds__(512, 2) void nets_kernel(
    const float* __restrict__ X,
    const int*   __restrict__ conn,
    const float* __restrict__ Wih,
    const float* __restrict__ Whh_f,
    const float* __restrict__ bih,
    const float* __restrict__ bhh,
    const float* __restrict__ Wlin,
    const float* __restrict__ blin,
    const float* __restrict__ znoise,
    const unsigned short* __restrict__ h1g,
    const float* __restrict__ Wmu_f,  const float* __restrict__ bmu,
    const float* __restrict__ Wstd_f, const float* __restrict__ bstd,
    const float* __restrict__ Wmean_f,const float* __restrict__ bmean,
    const float* __restrict__ Wdisp_f,const float* __restrict__ bdisp,
    float*       __restrict__ out)
{
    const int p    = blockIdx.x;
    const int b0   = blockIdx.y * 8;                 // 8 rows per block
    const int tid  = threadIdx.x;
    const int wave = tid >> 6;
    const int lane = tid & 63;
    const int quad = lane >> 4;
    const int ncol = lane & 15;
    const int j0   = wave * 32 + ncol;
    const int j1   = j0 + 16;

    __shared__ __align__(16) unsigned short hs[2][16][264];
    __shared__ __align__(16) unsigned short xs[2][16][16];
    __shared__ __align__(16) unsigned short wih_s[768][16];
    __shared__ float bR[256], bZ[256], bIN[256], bHN[256], wlin_s[256];
    __shared__ float predw[2][8][16];
    __shared__ int   conn_s[16];

    for (int i = tid; i < 768 * 16; i += 512)
        (&wih_s[0][0])[i] = f2bf_fast(Wih[p * 768 * 16 + i]);
    for (int i = tid; i < 256; i += 512) {
        bR[i]  = bih[p * 768 + i]       + bhh[p * 768 + i];
        bZ[i]  = bih[p * 768 + 256 + i] + bhh[p * 768 + 256 + i];
        bIN[i] = bih[p * 768 + 512 + i];
        bHN[i] = bhh[p * 768 + 512 + i];
        wlin_s[i] = Wlin[p * 256 + i];
    }
    if (tid < 16) conn_s[tid] = conn[p * 16 + tid];
    if (tid < 256) {                                 // zero BOTH x buffers
        xs[0][tid >> 4][tid & 15] = 0;               // (rows 8-15 never staged)
        xs[1][tid >> 4][tid & 15] = 0;
    }

    float hreg[2][4];

    // ---- prologue: heads from h1; z for this block's 8 rows (+8 dup rows) --
    {
        f32x4 acc_mu[2] = {{0,0,0,0},{0,0,0,0}};
        f32x4 acc_lv[2] = {{0,0,0,0},{0,0,0,0}};
        f32x4 acc_md[2] = {{0,0,0,0},{0,0,0,0}};
        const bool headp   = (p == 0);
        const bool do_mean = headp && (wave < 2);
        const bool do_disp = headp && (wave >= 2 && wave < 4);
        const int jm0 = (wave & 1) * 32 + ncol, jm1 = jm0 + 16;
        const int bnc = (b0 + ncol > 63) ? 63 : (b0 + ncol);  // A-row clamp

        #pragma unroll 2
        for (int ks = 0; ks < 8; ks++) {
            const int ko = ks * 32 + quad * 8;
            bf16x8 a = *(const bf16x8*)&h1g[(size_t)bnc * 256 + ko];
            #pragma unroll
            for (int s = 0; s < 2; s++) {
                const int j = s ? j1 : j0;
                bf16x8 bmu8 = pack8(Wmu_f  + (size_t)j * 256 + ko);
                bf16x8 blv8 = pack8(Wstd_f + (size_t)j * 256 + ko);
                acc_mu[s] = MFMA(a, bmu8, acc_mu[s]);
                acc_lv[s] = MFMA(a, blv8, acc_lv[s]);
                if (do_mean || do_disp) {
                    const int jm = s ? jm1 : jm0;
                    bf16x8 md8 = do_mean ? pack8(Wmean_f + (size_t)jm * 256 + ko)
                                         : pack8(Wdisp_f + (size_t)jm * 256 + ko);
                    acc_md[s] = MFMA(a, md8, acc_md[s]);
                }
            }
        }
        #pragma unroll
        for (int s = 0; s < 2; s++) {
            const int j = s ? j1 : j0;
            const float bmu_v = bmu[j], blv_v = bstd[j];
            #pragma unroll
            for (int r = 0; r < 4; r++) {
                const int row = quad * 4 + r;
                const int b  = b0 + row;
                const int bc = (b > 63) ? 63 : b;    // rows>=8: garbage lane
                float muv = acc_mu[s][r] + bmu_v;
                float lvv = acc_lv[s][r] + blv_v;
                if (headp && row < 8) {
                    out[OFF_MU + b * 256 + j] = muv;
                    out[OFF_LV + b * 256 + j] = lvv;
                }
                float zv = muv + __expf(0.5f * lvv) * znoise[bc * 256 + j];
                hreg[s][r] = zv;                     // nets h0 in registers
                hs[0][row][j] = f2bf(zv);            // nets h0 in LDS (cur=0)
            }
        }
        if (do_mean) {
            #pragma unroll
            for (int s = 0; s < 2; s++) {
                const int jm = s ? jm1 : jm0;
                const float bm = bmean[jm];
                #pragma unroll
                for (int r = 0; r < 4; r++) {
                    const int row = quad * 4 + r;
                    if (row < 8)
                        out[OFF_MEAN + (b0 + row) * 64 + jm] =
                            fminf(fmaxf(__expf(acc_md[s][r] + bm), 1e-5f), 1e6f);
                }
            }
        } else if (do_disp) {
            #pragma unroll
            for (int s = 0; s < 2; s++) {
                const int jm = s ? jm1 : jm0;
                const float bd = bdisp[jm];
                #pragma unroll
                for (int r = 0; r < 4; r++) {
                    const int row = quad * 4 + r;
                    if (row < 8) {
                        float v = acc_md[s][r] + bd;
                        float sp = (v > 20.f) ? v : log1pf(__expf(v));
                        out[OFF_DISP + (b0 + row) * 64 + jm] =
                            fminf(fmaxf(sp, 1e-4f), 1e4f);
                    }
                }
            }
        }
    }

    // preload W_hh fragments (loop-invariant, via pack8 from fp32)
    const size_t whh_off = (size_t)p * 768 * 256;
    bf16x8 w_r[2][8], w_z[2][8], w_n[2][8];
    #pragma unroll
    for (int s = 0; s < 2; s++) {
        const int j = s ? j1 : j0;
        #pragma unroll
        for (int k0 = 0; k0 < 8; k0++) {
            const int ko = k0 * 32 + quad * 8;
            w_r[s][k0] = pack8(Whh_f + whh_off + (size_t)(j)       * 256 + ko);
            w_z[s][k0] = pack8(Whh_f + whh_off + (size_t)(256 + j) * 256 + ko);
            w_n[s][k0] = pack8(Whh_f + whh_off + (size_t)(512 + j) * 256 + ko);
        }
    }

    __syncthreads();

    const float blin_v = blin[p];
    const bf16x8 ZERO8 = {0, 0, 0, 0, 0, 0, 0, 0};

    for (int t = 0; t < 100; t++) {
        const int cur = t & 1, nxt = cur ^ 1;
        f32x4 acc_r[2]  = {{0,0,0,0},{0,0,0,0}};
        f32x4 acc_z[2]  = {{0,0,0,0},{0,0,0,0}};
        f32x4 acc_in[2] = {{0,0,0,0},{0,0,0,0}};
        f32x4 acc_hn[2] = {{0,0,0,0},{0,0,0,0}};

        // x part (K=16 zero-padded)
        {
            bf16x8 a, br0, bz0, bn0, br1, bz1, bn1;
            if (quad < 2) {
                a   = *(const bf16x8*)&xs[cur][ncol][quad * 8];
                br0 = *(const bf16x8*)&wih_s[j0][quad * 8];
                bz0 = *(const bf16x8*)&wih_s[256 + j0][quad * 8];
                bn0 = *(const bf16x8*)&wih_s[512 + j0][quad * 8];
                br1 = *(const bf16x8*)&wih_s[j1][quad * 8];
                bz1 = *(const bf16x8*)&wih_s[256 + j1][quad * 8];
                bn1 = *(const bf16x8*)&wih_s[512 + j1][quad * 8];
            } else {
                a = ZERO8; br0 = bz0 = bn0 = br1 = bz1 = bn1 = ZERO8;
            }
            acc_r[0]  = MFMA(a, br0, acc_r[0]);  acc_r[1]  = MFMA(a, br1, acc_r[1]);
            acc_z[0]  = MFMA(a, bz0, acc_z[0]);  acc_z[1]  = MFMA(a, bz1, acc_z[1]);
            acc_in[0] = MFMA(a, bn0, acc_in[0]); acc_in[1] = MFMA(a, bn1, acc_in[1]);
        }
        // h part: weights from registers
        #pragma unroll
        for (int k0 = 0; k0 < 8; k0++) {
            bf16x8 a = *(const bf16x8*)&hs[cur][ncol][k0 * 32 + quad * 8];
            acc_r[0]  = MFMA(a, w_r[0][k0], acc_r[0]);
            acc_r[1]  = MFMA(a, w_r[1][k0], acc_r[1]);
            acc_z[0]  = MFMA(a, w_z[0][k0], acc_z[0]);
            acc_z[1]  = MFMA(a, w_z[1][k0], acc_z[1]);
            acc_hn[0] = MFMA(a, w_n[0][k0], acc_hn[0]);
            acc_hn[1] = MFMA(a, w_n[1][k0], acc_hn[1]);
        }

        // gates + state update
        float pv[4] = {0.f, 0.f, 0.f, 0.f};
        #pragma unroll
        for (int s = 0; s < 2; s++) {
            const int j = s ? j1 : j0;
            const float b_r = bR[j], b_z = bZ[j], b_in = bIN[j], b_hn = bHN[j];
            const float wl = wlin_s[j];
            #pragma unroll
            for (int r = 0; r < 4; r++) {
                float rg = sigm(acc_r[s][r] + b_r);
                float zg = sigm(acc_z[s][r] + b_z);
                float nn = tanh_fast(acc_in[s][r] + b_in + rg * (acc_hn[s][r] + b_hn));
                float hv = (1.f - zg) * nn + zg * hreg[s][r];
                hreg[s][r] = hv;
                pv[r] += fmaxf(hv, 0.f) * wl;
            }
        }
        // reduce across 16 ncol lanes: DPP row prefix-sum; sum in ncol==15
        #pragma unroll
        for (int r = 0; r < 4; r++)
            pv[r] = row_sum16(pv[r]);

        // writes into nxt buffers (disjoint from cur)
        #pragma unroll
        for (int r = 0; r < 4; r++) {
            hs[nxt][quad * 4 + r][j0] = f2bf_fast(hreg[0][r]);
            hs[nxt][quad * 4 + r][j1] = f2bf_fast(hreg[1][r]);
        }
        if (ncol == 15) {
            #pragma unroll
            for (int r = 0; r < 4; r++)
                predw[cur][wave][quad * 4 + r] = pv[r];
        }
        if (tid < 128) {                             // 8 rows x 16 k
            int gb = tid >> 4, gk = tid & 15;
            unsigned short v = 0;
            if (t < 99) v = f2bf_fast(X[(size_t)((b0 + gb) * 110 + (10 + t)) * 64 + conn_s[gk]]);
            xs[nxt][gb][gk] = v;
        }

        __syncthreads();   // orders: cur reads & nxt/predw[cur] writes

        if (tid < 8) {                               // 8 valid rows
            float s = blin_v;
            #pragma unroll
            for (int w = 0; w < 8; w++) s += predw[cur][w][tid];
            out[(size_t)(p * 64 + b0 + tid) * 100 + t] = s;
        }
    }
}

// ---------------------------------------------------------------------------
extern "C" void kernel_launch(void* const* d_in, const int* in_sizes, int n_in,
                              void* d_out, int out_size, void* d_ws, size_t ws_size,
                              hipStream_t stream) {
    const float* X      = (const float*)d_in[0];
    const int*   conn   = (const int*)d_in[1];
    const float* Wihl   = (const float*)d_in[2];
    const float* Whhl   = (const float*)d_in[3];
    const float* bihl   = (const float*)d_in[4];
    const float* bhhl   = (const float*)d_in[5];
    const float* Wih1   = (const float*)d_in[6];
    // d_in[7] = W_hh_1 unused: gru_1's h0 is 0, so gh reduces to b_hh_1
    const float* bih1   = (const float*)d_in[8];
    const float* bhh1   = (const float*)d_in[9];
    const float* Wmu    = (const float*)d_in[10];
    const float* bmu    = (const float*)d_in[11];
    const float* Wstd   = (const float*)d_in[12];
    const float* bstd   = (const float*)d_in[13];
    const float* Wmean  = (const float*)d_in[14];
    const float* bmean  = (const float*)d_in[15];
    const float* Wdisp  = (const float*)d_in[16];
    const float* bdisp  = (const float*)d_in[17];
    const float* Wihn   = (const float*)d_in[18];
    const float* Whhn   = (const float*)d_in[19];
    const float* bihn   = (const float*)d_in[20];
    const float* bhhn   = (const float*)d_in[21];
    const float* Wlin   = (const float*)d_in[22];
    const float* blin   = (const float*)d_in[23];
    const float* znoise = (const float*)d_in[24];

    float* out = (float*)d_out;
    unsigned short* h1ws = (unsigned short*)d_ws;   // 64*256 bf16 = 32 KB
    (void)ws_size;

    encoder_core<<<4, 512, 0, stream>>>(
        X, Wihl, Whhl, bihl, bhhl, Wih1, bih1, bhh1, h1ws);

    nets_kernel<<<dim3(64, 8), 512, 0, stream>>>(
        X, conn, Wihn, Whhn, bihn, bhhn, Wlin, blin, znoise,
        h1ws, Wmu, bmu, Wstd, bstd, Wmean, bmean, Wdisp, bdisp, out);
}

// Round 10
// 501.206 us; speedup vs baseline: 1.5977x; 1.5977x over previous
//
#include <hip/hip_runtime.h>

// ---------------------------------------------------------------------------
// GRANGER — R26: revert to R24-exact (best, 506.3 us).
// R25 post-mortem: grid (64,8) left OccupancyPercent at 23.5% — the second
// block NEVER co-resided. Root cause: VGPR_Count=128 is arch-VGPRs only; the
// W_hh fragments + accumulators live in the unified VGPR/AGPR file -> true
// usage ~256 regs/wave -> 2 waves/SIMD hard -> exactly ONE 512-thr block/CU.
// We paid 2x per-CU work at unchanged occupancy: nets 357 -> 681.
// Elimination tree now complete: spill x, barrier-drain x, DS-pipe x (exact
// null), skew/fusion x, register hoists -> spill, 2 blocks/CU -> impossible.
// Structure floor: 110-step serial recurrence, barrier-synchronized phases,
// 1 block/CU, register file exactly full.
// Output layout (fp32): pred[P,B,L,1] | log_var[B,H] | mu[B,H] | mean_[B,P]
// | disp_[B,P]
// ---------------------------------------------------------------------------

#define OFF_LV   409600
#define OFF_MU   425984
#define OFF_MEAN 442368
#define OFF_DISP 446464

typedef __attribute__((ext_vector_type(8))) short  bf16x8;
typedef __attribute__((ext_vector_type(4))) float  f32x4;

__device__ __forceinline__ float bf2f(unsigned short u) {
    union { unsigned int i; float f; } v; v.i = ((unsigned int)u) << 16; return v.f;
}
__device__ __forceinline__ unsigned short f2bf(float f) {
    union { float f; unsigned int i; } v; v.f = f;
    unsigned int x = v.i;
    return (unsigned short)((x + 0x7FFFu + ((x >> 16) & 1u)) >> 16);
}
__device__ __forceinline__ unsigned short f2bf_fast(float f) {
    return (unsigned short)((__float_as_uint(f) + 0x8000u) >> 16);
}
__device__ __forceinline__ bf16x8 pack8(const float* pf) {
    union { unsigned int u[4]; bf16x8 v; } r;
    const float4 a = *(const float4*)pf;
    const float4 b = *(const float4*)(pf + 4);
    r.u[0] = ((__float_as_uint(a.x) + 0x8000u) >> 16) | ((__float_as_uint(a.y) + 0x8000u) & 0xFFFF0000u);
    r.u[1] = ((__float_as_uint(a.z) + 0x8000u) >> 16) | ((__float_as_uint(a.w) + 0x8000u) & 0xFFFF0000u);
    r.u[2] = ((__float_as_uint(b.x) + 0x8000u) >> 16) | ((__float_as_uint(b.y) + 0x8000u) & 0xFFFF0000u);
    r.u[3] = ((__float_as_uint(b.z) + 0x8000u) >> 16) | ((__float_as_uint(b.w) + 0x8000u) & 0xFFFF0000u);
    return r.v;
}
__device__ __forceinline__ ushort4 f2bf4(float4 v) {
    ushort4 w;
    w.x = f2bf_fast(v.x); w.y = f2bf_fast(v.y);
    w.z = f2bf_fast(v.z); w.w = f2bf_fast(v.w);
    return w;
}
// rcpf-based, inf-safe
__device__ __forceinline__ float sigm(float x) {
    return __builtin_amdgcn_rcpf(1.0f + __expf(-x));
}
__device__ __forceinline__ float tanh_fast(float x) {
    return 2.0f * __builtin_amdgcn_rcpf(1.0f + __expf(-2.0f * x)) - 1.0f;
}
// Sum across the 16-lane DPP row via row_shr prefix adds (VALU pipe, no DS).
// Result valid in the LAST lane of each row (ncol==15). Verified R20/R21.
__device__ __forceinline__ float row_sum16(float v) {
    float t;
    t = __int_as_float(__builtin_amdgcn_update_dpp(0, __float_as_int(v), 0x111, 0xf, 0xf, true)); v += t; // shr:1
    t = __int_as_float(__builtin_amdgcn_update_dpp(0, __float_as_int(v), 0x112, 0xf, 0xf, true)); v += t; // shr:2
    t = __int_as_float(__builtin_amdgcn_update_dpp(0, __float_as_int(v), 0x114, 0xf, 0xf, true)); v += t; // shr:4
    t = __int_as_float(__builtin_amdgcn_update_dpp(0, __float_as_int(v), 0x118, 0xf, 0xf, true)); v += t; // shr:8
    return v;
}

#define MFMA(a, b, c) __builtin_amdgcn_mfma_f32_16x16x32_bf16((a), (b), (c), 0, 0, 0)

// ---------------------------------------------------------------------------
// Encoder core: 4 blocks (16 batch rows each) x 512 thr = 8 waves.
// Wave owns cols j0 = wave*32+ncol and j1 = j0+16.
// W_hh_left register-resident (at the 256-reg/wave cap, no spill);
// W_ih_left in LDS (stride 72). 10 steps + gru_1; h1 -> d_ws (bf16).
// Staging loops vectorized (float4 loads / ushort4 stores, bit-identical
// f2bf_fast rounding). Fragment mapping (HW-verified): A[m=lane&15][k=quad*8+i],
// D[m=quad*4+r][n=ncol].
// ---------------------------------------------------------------------------
__global__ __launch_bounds__(512, 1) void encoder_core(
    const float* __restrict__ X,
    const float* __restrict__ Wihl_f, const float* __restrict__ Whhl_f,
    const float* __restrict__ bihl,   const float* __restrict__ bhhl,
    const float* __restrict__ Wih1_f, const float* __restrict__ bih1,
    const float* __restrict__ bhh1,
    unsigned short* __restrict__ h1out)
{
    const int b0   = blockIdx.x * 16;
    const int tid  = threadIdx.x;
    const int wave = tid >> 6;
    const int lane = tid & 63;
    const int quad = lane >> 4;
    const int ncol = lane & 15;
    const int j0   = wave * 32 + ncol;
    const int j1   = j0 + 16;

    __shared__ __align__(16) unsigned short hs[2][16][264];
    __shared__ __align__(16) unsigned short xs[2][16][72];
    __shared__ __align__(16) unsigned short wihl_s[768][72];  // bf16, pad 64->72
    __shared__ float bR[256], bZ[256], bIN[256], bHN[256];
    __shared__ float b1R[256], b1Z[256], b1IN[256], b1HN[256];

    // stage W_ih_left -> LDS (bf16), 768x64, float4-vectorized
    {
        const float4* src = (const float4*)Wihl_f;
        for (int i = tid; i < 768 * 64 / 4; i += 512) {
            int idx = i * 4;
            int row = idx >> 6, col = idx & 63;          // col in {0,4,...,60}
            *(ushort4*)&wihl_s[row][col] = f2bf4(src[i]); // 8B-aligned (144B rows)
        }
    }
    for (int i = tid; i < 256; i += 512) {
        bR[i]   = bihl[i]       + bhhl[i];
        bZ[i]   = bihl[256 + i] + bhhl[256 + i];
        bIN[i]  = bihl[512 + i];
        bHN[i]  = bhhl[512 + i];
        b1R[i]  = bih1[i]       + bhh1[i];
        b1Z[i]  = bih1[256 + i] + bhh1[256 + i];
        b1IN[i] = bih1[512 + i];
        b1HN[i] = bhh1[512 + i];
    }
    for (int i = tid; i < 16 * 264; i += 512)
        (&hs[0][0][0])[i] = 0;                       // h0 = 0
    // xs init, float4-vectorized (256 chunks of 4 floats)
    for (int i = tid; i < 256; i += 512) {
        int b = i >> 4, f = (i & 15) * 4;
        float4 v = *(const float4*)&X[((size_t)(b0 + b) * 110 + 0) * 64 + f];
        *(ushort4*)&xs[0][b][f] = f2bf4(v);
    }

    // preload W_hh_left fragments into registers (loop-invariant, 192 regs)
    bf16x8 w_r[2][8], w_z[2][8], w_n[2][8];
    #pragma unroll
    for (int s = 0; s < 2; s++) {
        const int j = s ? j1 : j0;
        #pragma unroll
        for (int k0 = 0; k0 < 8; k0++) {
            const int ko = k0 * 32 + quad * 8;
            w_r[s][k0] = pack8(Whhl_f + (size_t)(j)       * 256 + ko);
            w_z[s][k0] = pack8(Whhl_f + (size_t)(256 + j) * 256 + ko);
            w_n[s][k0] = pack8(Whhl_f + (size_t)(512 + j) * 256 + ko);
        }
    }

    float hreg[2][4];
    #pragma unroll
    for (int s = 0; s < 2; s++)
        #pragma unroll
        for (int r = 0; r < 4; r++) hreg[s][r] = 0.f;

    __syncthreads();

    // ---- gru_left: 10 MFMA steps, zero global traffic in compute ----
    for (int t = 0; t < 10; t++) {
        const int cur = t & 1, nxt = cur ^ 1;
        f32x4 acc_r[2]  = {{0,0,0,0},{0,0,0,0}};
        f32x4 acc_z[2]  = {{0,0,0,0},{0,0,0,0}};
        f32x4 acc_in[2] = {{0,0,0,0},{0,0,0,0}};
        f32x4 acc_hn[2] = {{0,0,0,0},{0,0,0,0}};

        // x part: k = 64 -> 2 k-steps (weights from LDS)
        #pragma unroll
        for (int ks = 0; ks < 2; ks++) {
            const int ko = ks * 32 + quad * 8;
            bf16x8 a = *(const bf16x8*)&xs[cur][ncol][ko];
            #pragma unroll
            for (int s = 0; s < 2; s++) {
                const int j = s ? j1 : j0;
                bf16x8 br = *(const bf16x8*)&wihl_s[j][ko];
                bf16x8 bz = *(const bf16x8*)&wihl_s[256 + j][ko];
                bf16x8 bn = *(const bf16x8*)&wihl_s[512 + j][ko];
                acc_r[s]  = MFMA(a, br, acc_r[s]);
                acc_z[s]  = MFMA(a, bz, acc_z[s]);
                acc_in[s] = MFMA(a, bn, acc_in[s]);
            }
        }
        // h part: weights from registers
        #pragma unroll
        for (int ks = 0; ks < 8; ks++) {
            bf16x8 a = *(const bf16x8*)&hs[cur][ncol][ks * 32 + quad * 8];
            #pragma unroll
            for (int s = 0; s < 2; s++) {
                acc_r[s]  = MFMA(a, w_r[s][ks], acc_r[s]);
                acc_z[s]  = MFMA(a, w_z[s][ks], acc_z[s]);
                acc_hn[s] = MFMA(a, w_n[s][ks], acc_hn[s]);
            }
        }
        // epilogue + state write
        #pragma unroll
        for (int s = 0; s < 2; s++) {
            const int j = s ? j1 : j0;
            #pragma unroll
            for (int r = 0; r < 4; r++) {
                float rg = sigm(acc_r[s][r] + bR[j]);
                float zg = sigm(acc_z[s][r] + bZ[j]);
                float nn = tanh_fast(acc_in[s][r] + bIN[j] + rg * (acc_hn[s][r] + bHN[j]));
                float hv = (1.f - zg) * nn + zg * hreg[s][r];
                hreg[s][r] = hv;
                hs[nxt][quad * 4 + r][j] = f2bf(hv);
            }
        }
        if (t < 9)
            for (int i = tid; i < 256; i += 512) {
                int b = i >> 4, f = (i & 15) * 4;
                float4 v = *(const float4*)&X[((size_t)(b0 + b) * 110 + (t + 1)) * 64 + f];
                *(ushort4*)&xs[nxt][b][f] = f2bf4(v);
            }
        __syncthreads();
    }
    // h_left in hs[0] (t=9: nxt=0)

    // ---- gru_1: one step, input h_left, h0 = 0 (gh = b_hh_1) ----
    {
        f32x4 acc_r[2]  = {{0,0,0,0},{0,0,0,0}};
        f32x4 acc_z[2]  = {{0,0,0,0},{0,0,0,0}};
        f32x4 acc_in[2] = {{0,0,0,0},{0,0,0,0}};
        #pragma unroll 2
        for (int ks = 0; ks < 8; ks++) {
            const int ko = ks * 32 + quad * 8;
            bf16x8 a = *(const bf16x8*)&hs[0][ncol][ko];
            #pragma unroll
            for (int s = 0; s < 2; s++) {
                const int j = s ? j1 : j0;
                bf16x8 br = pack8(Wih1_f + (size_t)(j)       * 256 + ko);
                bf16x8 bz = pack8(Wih1_f + (size_t)(256 + j) * 256 + ko);
                bf16x8 bn = pack8(Wih1_f + (size_t)(512 + j) * 256 + ko);
                acc_r[s]  = MFMA(a, br, acc_r[s]);
                acc_z[s]  = MFMA(a, bz, acc_z[s]);
                acc_in[s] = MFMA(a, bn, acc_in[s]);
            }
        }
        #pragma unroll
        for (int s = 0; s < 2; s++) {
            const int j = s ? j1 : j0;
            #pragma unroll
            for (int r = 0; r < 4; r++) {
                float rg = sigm(acc_r[s][r] + b1R[j]);
                float zg = sigm(acc_z[s][r] + b1Z[j]);
                float nn = tanh_fast(acc_in[s][r] + b1IN[j] + rg * b1HN[j]);
                float hv = (1.f - zg) * nn;           // + zg*0
                hs[1][quad * 4 + r][j] = f2bf(hv);
            }
        }
        __syncthreads();   // h1 in hs[1]
    }

    // ---- h1 -> workspace (bf16, same bits the heads consumed before) ----
    for (int i = tid; i < 16 * 256; i += 512) {
        int row = i >> 8, j = i & 255;
        h1out[(size_t)(b0 + row) * 256 + j] = hs[1][row][j];
    }
}

// ---------------------------------------------------------------------------
// Nets: R21-exact (known-good 351.7 us). grid (p=64, btile=4) = 256 blocks,
// 512 thr, launch_bounds(512,2). One block/CU (unified-regfile bound).
// ---------------------------------------------------------------------------
__global__ __launch_bounds__(512, 2) void nets_kernel(
    const float* __restrict__ X,
    const int*   __restrict__ conn,
    const float* __restrict__ Wih,
    const float* __restrict__ Whh_f,
    const float* __restrict__ bih,
    const float* __restrict__ bhh,
    const float* __restrict__ Wlin,
    const float* __restrict__ blin,
    const float* __restrict__ znoise,
    const unsigned short* __restrict__ h1g,
    const float* __restrict__ Wmu_f,  const float* __restrict__ bmu,
    const float* __restrict__ Wstd_f, const float* __restrict__ bstd,
    const float* __restrict__ Wmean_f,const float* __restrict__ bmean,
    const float* __restrict__ Wdisp_f,const float* __restrict__ bdisp,
    float*       __restrict__ out)
{
    const int p    = blockIdx.x;
    const int b0   = blockIdx.y * 16;
    const int tid  = threadIdx.x;
    const int wave = tid >> 6;
    const int lane = tid & 63;
    const int quad = lane >> 4;
    const int ncol = lane & 15;
    const int j0   = wave * 32 + ncol;
    const int j1   = j0 + 16;

    __shared__ __align__(16) unsigned short hs[2][16][264];
    __shared__ __align__(16) unsigned short xs[2][16][16];
    __shared__ __align__(16) unsigned short wih_s[768][16];
    __shared__ float bR[256], bZ[256], bIN[256], bHN[256], wlin_s[256];
    __shared__ float predw[2][8][16];
    __shared__ int   conn_s[16];

    for (int i = tid; i < 768 * 16; i += 512)
        (&wih_s[0][0])[i] = f2bf_fast(Wih[p * 768 * 16 + i]);
    for (int i = tid; i < 256; i += 512) {
        bR[i]  = bih[p * 768 + i]       + bhh[p * 768 + i];
        bZ[i]  = bih[p * 768 + 256 + i] + bhh[p * 768 + 256 + i];
        bIN[i] = bih[p * 768 + 512 + i];
        bHN[i] = bhh[p * 768 + 512 + i];
        wlin_s[i] = Wlin[p * 256 + i];
    }
    if (tid < 16) conn_s[tid] = conn[p * 16 + tid];
    if (tid < 256) xs[0][tid >> 4][tid & 15] = 0;

    float hreg[2][4];

    // ---- prologue: heads from h1 (replaces out[MU]/out[LV] round-trip) ----
    {
        f32x4 acc_mu[2] = {{0,0,0,0},{0,0,0,0}};
        f32x4 acc_lv[2] = {{0,0,0,0},{0,0,0,0}};
        f32x4 acc_md[2] = {{0,0,0,0},{0,0,0,0}};
        const bool headp   = (p == 0);
        const bool do_mean = headp && (wave < 2);
        const bool do_disp = headp && (wave >= 2 && wave < 4);
        const int jm0 = (wave & 1) * 32 + ncol, jm1 = jm0 + 16;

        #pragma unroll 2
        for (int ks = 0; ks < 8; ks++) {
            const int ko = ks * 32 + quad * 8;
            bf16x8 a = *(const bf16x8*)&h1g[(size_t)(b0 + ncol) * 256 + ko];
            #pragma unroll
            for (int s = 0; s < 2; s++) {
                const int j = s ? j1 : j0;
                bf16x8 bmu8 = pack8(Wmu_f  + (size_t)j * 256 + ko);
                bf16x8 blv8 = pack8(Wstd_f + (size_t)j * 256 + ko);
                acc_mu[s] = MFMA(a, bmu8, acc_mu[s]);
                acc_lv[s] = MFMA(a, blv8, acc_lv[s]);
                if (do_mean || do_disp) {
                    const int jm = s ? jm1 : jm0;
                    bf16x8 md8 = do_mean ? pack8(Wmean_f + (size_t)jm * 256 + ko)
                                         : pack8(Wdisp_f + (size_t)jm * 256 + ko);
                    acc_md[s] = MFMA(a, md8, acc_md[s]);
                }
            }
        }
        #pragma unroll
        for (int s = 0; s < 2; s++) {
            const int j = s ? j1 : j0;
            const float bmu_v = bmu[j], blv_v = bstd[j];
            #pragma unroll
            for (int r = 0; r < 4; r++) {
                const int row = quad * 4 + r, b = b0 + row;
                float muv = acc_mu[s][r] + bmu_v;
                float lvv = acc_lv[s][r] + blv_v;
                if (headp) {
                    out[OFF_MU + b * 256 + j] = muv;
                    out[OFF_LV + b * 256 + j] = lvv;
                }
                float zv = muv + __expf(0.5f * lvv) * znoise[b * 256 + j];
                hreg[s][r] = zv;                     // nets h0 in registers
                hs[0][row][j] = f2bf(zv);            // nets h0 in LDS (cur=0)
            }
        }
        if (do_mean) {
            #pragma unroll
            for (int s = 0; s < 2; s++) {
                const int jm = s ? jm1 : jm0;
                const float bm = bmean[jm];
                #pragma unroll
                for (int r = 0; r < 4; r++) {
                    int b = b0 + quad * 4 + r;
                    out[OFF_MEAN + b * 64 + jm] =
                        fminf(fmaxf(__expf(acc_md[s][r] + bm), 1e-5f), 1e6f);
                }
            }
        } else if (do_disp) {
            #pragma unroll
            for (int s = 0; s < 2; s++) {
                const int jm = s ? jm1 : jm0;
                const float bd = bdisp[jm];
                #pragma unroll
                for (int r = 0; r < 4; r++) {
                    int b = b0 + quad * 4 + r;
                    float v = acc_md[s][r] + bd;
                    float sp = (v > 20.f) ? v : log1pf(__expf(v));
                    out[OFF_DISP + b * 64 + jm] = fminf(fmaxf(sp, 1e-4f), 1e4f);
                }
            }
        }
    }

    // preload W_hh fragments (loop-invariant, via pack8 from fp32)
    const size_t whh_off = (size_t)p * 768 * 256;
    bf16x8 w_r[2][8], w_z[2][8], w_n[2][8];
    #pragma unroll
    for (int s = 0; s < 2; s++) {
        const int j = s ? j1 : j0;
        #pragma unroll
        for (int k0 = 0; k0 < 8; k0++) {
            const int ko = k0 * 32 + quad * 8;
            w_r[s][k0] = pack8(Whh_f + whh_off + (size_t)(j)       * 256 + ko);
            w_z[s][k0] = pack8(Whh_f + whh_off + (size_t)(256 + j) * 256 + ko);
            w_n[s][k0] = pack8(Whh_f + whh_off + (size_t)(512 + j) * 256 + ko);
        }
    }

    __syncthreads();

    const float blin_v = blin[p];
    const bf16x8 ZERO8 = {0, 0, 0, 0, 0, 0, 0, 0};

    for (int t = 0; t < 100; t++) {
        const int cur = t & 1, nxt = cur ^ 1;
        f32x4 acc_r[2]  = {{0,0,0,0},{0,0,0,0}};
        f32x4 acc_z[2]  = {{0,0,0,0},{0,0,0,0}};
        f32x4 acc_in[2] = {{0,0,0,0},{0,0,0,0}};
        f32x4 acc_hn[2] = {{0,0,0,0},{0,0,0,0}};

        // x part (K=16 zero-padded)
        {
            bf16x8 a, br0, bz0, bn0, br1, bz1, bn1;
            if (quad < 2) {
                a   = *(const bf16x8*)&xs[cur][ncol][quad * 8];
                br0 = *(const bf16x8*)&wih_s[j0][quad * 8];
                bz0 = *(const bf16x8*)&wih_s[256 + j0][quad * 8];
                bn0 = *(const bf16x8*)&wih_s[512 + j0][quad * 8];
                br1 = *(const bf16x8*)&wih_s[j1][quad * 8];
                bz1 = *(const bf16x8*)&wih_s[256 + j1][quad * 8];
                bn1 = *(const bf16x8*)&wih_s[512 + j1][quad * 8];
            } else {
                a = ZERO8; br0 = bz0 = bn0 = br1 = bz1 = bn1 = ZERO8;
            }
            acc_r[0]  = MFMA(a, br0, acc_r[0]);  acc_r[1]  = MFMA(a, br1, acc_r[1]);
            acc_z[0]  = MFMA(a, bz0, acc_z[0]);  acc_z[1]  = MFMA(a, bz1, acc_z[1]);
            acc_in[0] = MFMA(a, bn0, acc_in[0]); acc_in[1] = MFMA(a, bn1, acc_in[1]);
        }
        // h part: weights from registers
        #pragma unroll
        for (int k0 = 0; k0 < 8; k0++) {
            bf16x8 a = *(const bf16x8*)&hs[cur][ncol][k0 * 32 + quad * 8];
            acc_r[0]  = MFMA(a, w_r[0][k0], acc_r[0]);
            acc_r[1]  = MFMA(a, w_r[1][k0], acc_r[1]);
            acc_z[0]  = MFMA(a, w_z[0][k0], acc_z[0]);
            acc_z[1]  = MFMA(a, w_z[1][k0], acc_z[1]);
            acc_hn[0] = MFMA(a, w_n[0][k0], acc_hn[0]);
            acc_hn[1] = MFMA(a, w_n[1][k0], acc_hn[1]);
        }

        // gates + state update
        float pv[4] = {0.f, 0.f, 0.f, 0.f};
        #pragma unroll
        for (int s = 0; s < 2; s++) {
            const int j = s ? j1 : j0;
            const float b_r = bR[j], b_z = bZ[j], b_in = bIN[j], b_hn = bHN[j];
            const float wl = wlin_s[j];
            #pragma unroll
            for (int r = 0; r < 4; r++) {
                float rg = sigm(acc_r[s][r] + b_r);
                float zg = sigm(acc_z[s][r] + b_z);
                float nn = tanh_fast(acc_in[s][r] + b_in + rg * (acc_hn[s][r] + b_hn));
                float hv = (1.f - zg) * nn + zg * hreg[s][r];
                hreg[s][r] = hv;
                pv[r] += fmaxf(hv, 0.f) * wl;
            }
        }
        // reduce across 16 ncol lanes: DPP row prefix-sum (VALU pipe, no DS);
        // full sum lands in ncol==15
        #pragma unroll
        for (int r = 0; r < 4; r++)
            pv[r] = row_sum16(pv[r]);

        // writes into nxt buffers (disjoint from cur)
        #pragma unroll
        for (int r = 0; r < 4; r++) {
            hs[nxt][quad * 4 + r][j0] = f2bf_fast(hreg[0][r]);
            hs[nxt][quad * 4 + r][j1] = f2bf_fast(hreg[1][r]);
        }
        if (ncol == 15) {
            #pragma unroll
            for (int r = 0; r < 4; r++)
                predw[cur][wave][quad * 4 + r] = pv[r];
        }
        if (tid < 256) {
            int gb = tid >> 4, gk = tid & 15;
            unsigned short v = 0;
            if (t < 99) v = f2bf_fast(X[(size_t)((b0 + gb) * 110 + (10 + t)) * 64 + conn_s[gk]]);
            xs[nxt][gb][gk] = v;
        }

        __syncthreads();   // orders: cur reads & nxt/predw[cur] writes

        if (tid < 16) {
            float s = blin_v;
            #pragma unroll
            for (int w = 0; w < 8; w++) s += predw[cur][w][tid];
            out[(size_t)(p * 64 + b0 + tid) * 100 + t] = s;
        }
    }
}

// ---------------------------------------------------------------------------
extern "C" void kernel_launch(void* const* d_in, const int* in_sizes, int n_in,
                              void* d_out, int out_size, void* d_ws, size_t ws_size,
                              hipStream_t stream) {
    const float* X      = (const float*)d_in[0];
    const int*   conn   = (const int*)d_in[1];
    const float* Wihl   = (const float*)d_in[2];
    const float* Whhl   = (const float*)d_in[3];
    const float* bihl   = (const float*)d_in[4];
    const float* bhhl   = (const float*)d_in[5];
    const float* Wih1   = (const float*)d_in[6];
    // d_in[7] = W_hh_1 unused: gru_1's h0 is 0, so gh reduces to b_hh_1
    const float* bih1   = (const float*)d_in[8];
    const float* bhh1   = (const float*)d_in[9];
    const float* Wmu    = (const float*)d_in[10];
    const float* bmu    = (const float*)d_in[11];
    const float* Wstd   = (const float*)d_in[12];
    const float* bstd   = (const float*)d_in[13];
    const float* Wmean  = (const float*)d_in[14];
    const float* bmean  = (const float*)d_in[15];
    const float* Wdisp  = (const float*)d_in[16];
    const float* bdisp  = (const float*)d_in[17];
    const float* Wihn   = (const float*)d_in[18];
    const float* Whhn   = (const float*)d_in[19];
    const float* bihn   = (const float*)d_in[20];
    const float* bhhn   = (const float*)d_in[21];
    const float* Wlin   = (const float*)d_in[22];
    const float* blin   = (const float*)d_in[23];
    const float* znoise = (const float*)d_in[24];

    float* out = (float*)d_out;
    unsigned short* h1ws = (unsigned short*)d_ws;   // 64*256 bf16 = 32 KB
    (void)ws_size;

    encoder_core<<<4, 512, 0, stream>>>(
        X, Wihl, Whhl, bihl, bhhl, Wih1, bih1, bhh1, h1ws);

    nets_kernel<<<dim3(64, 4), 512, 0, stream>>>(
        X, conn, Wihn, Whhn, bihn, bhhn, Wlin, blin, znoise,
        h1ws, Wmu, bmu, Wstd, bstd, Wmean, bmean, Wdisp, bdisp, out);
}